// Round 2
// baseline (492.461 us; speedup 1.0000x reference)
//
#include <hip/hip_runtime.h>
#include <stdint.h>

// GaussianTrans R5: out[b,r,c,d] = sum_h sig(disX[c,h]+attX[b,r,c,h]) * V[b,r,h,d]
//                                + sum_w sig(disY[r,w]+attY[b,c,r,w]) * V[b,w,c,d]
// B=16, H=W=64, D=512. fp32 I/O; bf16 MFMA, fp32 accum, fp16 X-partial park.
// Structure: 3 prep passes + 1 barrier-free MFMA pass.
//   prep_sig : A' = bf16(sigmoid(dis+att)) for both tensors   (ws)
//   retile x2: VtX[b][r][d][h] = bf16 V[b][r][h][d]; VtY[b][c][d][w] = bf16 V[b][w][c][d]
//   gauss_mfma: 1-wave blocks, ALL MFMA operands are direct coalesced 16B global
//   loads (L2-served; A'[b] pinned per-XCD). X-partial parked in 8.4KB LDS
//   (intra-wave, no __syncthreads anywhere). One f32x4 out store per lane per cc.
// R4 failed on occupancy: 128KB LDS -> 1 block/CU, 8 barrier drains/iter, 2.1TB/s.
// Here: ~18 blocks/CU by LDS, zero barriers, loads pipeline freely.

typedef __attribute__((ext_vector_type(8))) __bf16 bf16x8;
typedef __attribute__((ext_vector_type(8))) short short8;
typedef __attribute__((ext_vector_type(4))) float f32x4;
typedef __attribute__((ext_vector_type(4))) unsigned int uint4v;
typedef __attribute__((ext_vector_type(4))) unsigned short u16x4;

union U8 { short8 s; bf16x8 b; unsigned short u[8]; uint4v q; };

__device__ __forceinline__ unsigned short f2bf(float f) {
    union { float f; unsigned int i; } v; v.f = f;
    return (unsigned short)((v.i + 0x7fffu + ((v.i >> 16) & 1u)) >> 16);  // RNE
}
__device__ __forceinline__ float fsigmoid(float x) {
    float e = __builtin_amdgcn_exp2f(-1.44269504f * x);   // exp(-x)
    return __builtin_amdgcn_rcpf(1.0f + e);
}
__device__ __forceinline__ unsigned short f2h(float f) {
    union { _Float16 h; unsigned short u; } v; v.h = (_Float16)f; return v.u;
}
__device__ __forceinline__ float h2f(unsigned short u) {
    union { _Float16 h; unsigned short us; } v; v.us = u; return (float)v.h;
}

// ---------------- prep: A' = bf16(sigmoid(dis + att)) ----------------
__device__ __forceinline__ void sig16(const float* __restrict__ in,
                                      unsigned short* __restrict__ outp,
                                      int l0, int sec, float shift, float bias) {
    f32x4 v[4];
#pragma unroll
    for (int j = 0; j < 4; ++j) v[j] = *(const f32x4*)(in + 4 * j);
    U8 r0, r1;
#pragma unroll
    for (int e = 0; e < 16; ++e) {
        float dd = (float)(l0 + e - sec);
        float dis = -(shift * dd * dd + bias);
        unsigned short us = f2bf(fsigmoid(dis + v[e >> 2][e & 3]));
        if (e < 8) r0.u[e] = us; else r1.u[e - 8] = us;
    }
    *(uint4v*)(outp) = r0.q;
    *(uint4v*)(outp + 8) = r1.q;
}

__global__ __launch_bounds__(256)
void prep_sig(const float* __restrict__ attX, const float* __restrict__ attY,
              unsigned short* __restrict__ aX, unsigned short* __restrict__ aY,
              const float* __restrict__ shiftp, const float* __restrict__ biasp) {
    const float shift = shiftp[0];
    const float bias  = biasp[0];
    const size_t base = ((size_t)blockIdx.x * 256 + threadIdx.x) * 16;
    const int sec = (int)((base >> 6) & 63);
    const int l0  = (int)(base & 63);
    sig16(attX + base, aX + base, l0, sec, shift, bias);
    sig16(attY + base, aY + base, l0, sec, shift, bias);
}

// ---------------- retile: vt[p][d][j] = bf16(src_panel[j][d]) ----------------
// Panel p: src base = (p>>6)*strideB + (p&63)*strideI; row j at + j*rowStride.
//   X: strideB=2097152, strideI=32768, rowStride=512   (p = b*64+r, j=h)
//   Y: strideB=2097152, strideI=512,   rowStride=32768 (p = b*64+c, j=w)
// Output panel p: vt + p*32768 u16, layout [d512][j64].
__global__ __launch_bounds__(256)
void retile(const float* __restrict__ V, unsigned short* __restrict__ vt,
            long long rowStride, long long strideB, long long strideI) {
    __shared__ unsigned short T[64 * 72];  // [j][72] pad: 16B-aligned rows
    const int p = blockIdx.x;
    const int t = threadIdx.x;
    const float* src = V + (size_t)(p >> 6) * strideB + (size_t)(p & 63) * strideI;
    unsigned short* dst = vt + (size_t)p * 32768;

    for (int ch = 0; ch < 8; ++ch) {           // 64-wide d chunks
        const int j = t >> 2, qq = t & 3;      // read 64 j x 64 d fp32
        const float* sp = src + (size_t)j * rowStride + ch * 64 + qq * 16;
        f32x4 x[4];
#pragma unroll
        for (int k = 0; k < 4; ++k) x[k] = *(const f32x4*)(sp + 4 * k);
        if (ch) __syncthreads();               // prior readers done before overwrite
        U8 w0, w1;
#pragma unroll
        for (int e = 0; e < 8; ++e) {
            w0.u[e] = f2bf(x[e >> 2][e & 3]);
            w1.u[e] = f2bf(x[2 + (e >> 2)][e & 3]);
        }
        *(uint4v*)(&T[j * 72 + qq * 16])     = w0.q;
        *(uint4v*)(&T[j * 72 + qq * 16 + 8]) = w1.q;
        __syncthreads();
        const int d = t >> 2, part = t & 3;    // write 64 d-rows x 64 j bf16
        U8 o0, o1;
#pragma unroll
        for (int jj = 0; jj < 8; ++jj) {
            o0.u[jj] = T[(part * 16 + jj) * 72 + d];
            o1.u[jj] = T[(part * 16 + 8 + jj) * 72 + d];
        }
        unsigned short* dp = dst + (size_t)(ch * 64 + d) * 64 + part * 16;
        *(uint4v*)dp       = o0.q;
        *(uint4v*)(dp + 8) = o1.q;
    }
}

// ---------------- main: barrier-free per-wave MFMA pass ----------------
// Block = 1 wave, owns out[b, rt*16+0..15, ct*16+0..15, dt*16+0..15].
// X: D[m=d][n=c] = sum_h VtX[b][r][d][h] * A'X[b][r][c][h]  (per r; 2 MFMA, K=64)
//    park (r, d=quad*4+g, c=l15) -> olds[r*264 + c*16 + d]  (b64, intra-wave)
// Y: D[m=d][n=r] = sum_w VtY[b][c][d][w] * A'Y[b][c][r][w]  (per c; 2 MFMA)
//    epilogue: res[g] = accY[g] + fp16 park[l15*264 + cc*16 + quad*4+g]; f32x4 store.
// Operand layouts (HW-verified in R4): A-frag row=l15, k=quad*8+j; B-frag col=l15,
// k=quad*8+j; C/D row=quad*4+reg, col=l15.
__global__ __launch_bounds__(64, 4)
void gauss_mfma(const unsigned short* __restrict__ aX,
                const unsigned short* __restrict__ aY,
                const unsigned short* __restrict__ vtX,
                const unsigned short* __restrict__ vtY,
                float* __restrict__ out) {
    __shared__ unsigned short olds[16 * 264 + 8];  // [f16][c16][d16], frag stride 264

    // XCD-pinned decode: p%8 -> XCD; each XCD runs 2 b's sequentially, dt-major so
    // A'[b] (1MB) stays L2-resident across all 32 d-tiles of that b.
    const int p  = blockIdx.x;
    const int b  = (p & 7) + (((p >> 3) >> 9) << 3);
    const int q  = (p >> 3) & 511;
    const int dt = q >> 4;
    const int rt = (q >> 2) & 3;
    const int ct = q & 3;

    const int lane = threadIdx.x;
    const int l15 = lane & 15, quad = lane >> 4;
    const int dlo = dt * 16 + l15;

    // ---- X phase ----
#pragma unroll
    for (int rr = 0; rr < 16; ++rr) {
        const int r = rt * 16 + rr;
        const unsigned short* vp = vtX + ((size_t)(b * 64 + r) * 512 + dlo) * 64 + quad * 8;
        const unsigned short* ap = aX + ((size_t)(b * 64 + r) * 64 + ct * 16 + l15) * 64 + quad * 8;
        U8 v0, v1, a0, a1;
        v0.q = *(const uint4v*)vp;
        v1.q = *(const uint4v*)(vp + 32);
        a0.q = *(const uint4v*)ap;
        a1.q = *(const uint4v*)(ap + 32);
        f32x4 acc = (f32x4)0.0f;
        acc = __builtin_amdgcn_mfma_f32_16x16x32_bf16(v0.b, a0.b, acc, 0, 0, 0);
        acc = __builtin_amdgcn_mfma_f32_16x16x32_bf16(v1.b, a1.b, acc, 0, 0, 0);
        u16x4 pk;
#pragma unroll
        for (int g = 0; g < 4; ++g) pk[g] = f2h(acc[g]);
        *(u16x4*)&olds[rr * 264 + l15 * 16 + quad * 4] = pk;
    }

    // ---- Y phase + epilogue (intra-wave LDS dep: compiler waitcnt, no barrier) ----
    float* ob = out + (size_t)b * 2097152 + (size_t)(rt * 16 + l15) * 32768
              + (size_t)(ct * 16) * 512 + dt * 16 + quad * 4;
#pragma unroll
    for (int cc = 0; cc < 16; ++cc) {
        const int c = ct * 16 + cc;
        const unsigned short* wp = vtY + ((size_t)(b * 64 + c) * 512 + dlo) * 64 + quad * 8;
        const unsigned short* bp = aY + ((size_t)(b * 64 + c) * 64 + rt * 16 + l15) * 64 + quad * 8;
        U8 w0, w1, y0, y1;
        w0.q = *(const uint4v*)wp;
        w1.q = *(const uint4v*)(wp + 32);
        y0.q = *(const uint4v*)bp;
        y1.q = *(const uint4v*)(bp + 32);
        f32x4 acc = (f32x4)0.0f;
        acc = __builtin_amdgcn_mfma_f32_16x16x32_bf16(w0.b, y0.b, acc, 0, 0, 0);
        acc = __builtin_amdgcn_mfma_f32_16x16x32_bf16(w1.b, y1.b, acc, 0, 0, 0);
        u16x4 xp = *(const u16x4*)&olds[l15 * 264 + cc * 16 + quad * 4];
        f32x4 res;
#pragma unroll
        for (int g = 0; g < 4; ++g) res[g] = acc[g] + h2f(xp[g]);
        *(f32x4*)(ob + (size_t)cc * 512) = res;
    }
}

// ---------------- fallback (ws too small): proven two-pass kernel ----------------
template <int S_I, int S_K, bool ACCUM>
__global__ __launch_bounds__(256)
void gauss_gemm(const float* __restrict__ att,
                const float* __restrict__ V,
                float* __restrict__ out,
                const float* __restrict__ shiftp,
                const float* __restrict__ biasp) {
    __shared__ unsigned short S[4096];
    __shared__ unsigned short VT[128 * 66];

    const int bid    = blockIdx.x;
    const int dq     = bid & 3;
    const int i      = (bid >> 2) & 63;
    const int b      = bid >> 8;
    const int t      = threadIdx.x;
    const int dstart = dq * 128;

    const float shift = shiftp[0];
    const float bias  = biasp[0];
    const size_t base = (size_t)b * 2097152 + (size_t)i * S_I;

    const float* ab = att + (size_t)(b * 64 + i) * 4096;
#pragma unroll
    for (int chunk = 0; chunk < 2; ++chunk) {
        int flat = t + chunk * 256;
        int qd = flat >> 6, m = flat & 63;
        const float* ap = ab + m * 64 + qd * 8;
        f32x4 av0 = *(const f32x4*)(ap);
        f32x4 av1 = *(const f32x4*)(ap + 4);
        U8 res;
#pragma unroll
        for (int j = 0; j < 8; ++j) {
            float a    = (j < 4) ? av0[j & 3] : av1[j & 3];
            float diff = (float)(qd * 8 + j - m);
            float dis  = -(shift * diff * diff + bias);
            res.u[j]   = f2bf(fsigmoid(dis + a));
        }
        *(short8*)(&S[flat * 8]) = res.s;
    }
    {
        const float* vb = V + base + dstart;
        const int d4 = t & 31;
        const int h0 = t >> 5;
#pragma unroll
        for (int it = 0; it < 8; ++it) {
            const int h = h0 + it * 8;
            f32x4 v = *(const f32x4*)(vb + (size_t)h * S_K + 4 * d4);
#pragma unroll
            for (int u = 0; u < 4; ++u)
                VT[(4 * d4 + u) * 66 + h] = f2bf(v[u]);
        }
    }
    __syncthreads();

    const int lane = t & 63, wid = t >> 6;
    const int l15 = lane & 15, quad = lane >> 4;

    f32x4 acc[4][2];
#pragma unroll
    for (int mt = 0; mt < 4; ++mt)
#pragma unroll
        for (int nt = 0; nt < 2; ++nt) acc[mt][nt] = (f32x4)0.0f;

#pragma unroll
    for (int ks = 0; ks < 2; ++ks) {
        bf16x8 af[4];
#pragma unroll
        for (int mt = 0; mt < 4; ++mt) {
            U8 a;
            a.s = *(const short8*)(&S[((ks * 4 + quad) * 64 + mt * 16 + l15) * 8]);
            af[mt] = a.b;
        }
        const int h = ks * 32 + quad * 8;
#pragma unroll
        for (int nt = 0; nt < 2; ++nt) {
            const int dloc = wid * 32 + nt * 16 + l15;
            const unsigned short* vp = &VT[dloc * 66 + h];
            U8 bvec;
            uint4v qv;
#pragma unroll
            for (int u = 0; u < 4; ++u) qv[u] = *(const unsigned int*)(vp + 2 * u);
            bvec.q = qv;
#pragma unroll
            for (int mt = 0; mt < 4; ++mt)
                acc[mt][nt] = __builtin_amdgcn_mfma_f32_16x16x32_bf16(
                    af[mt], bvec.b, acc[mt][nt], 0, 0, 0);
        }
    }

    float* ob = out + base + dstart;
#pragma unroll
    for (int mt = 0; mt < 4; ++mt)
#pragma unroll
        for (int nt = 0; nt < 2; ++nt)
#pragma unroll
            for (int reg = 0; reg < 4; ++reg) {
                int m = mt * 16 + quad * 4 + reg;
                int d = wid * 32 + nt * 16 + l15;
                size_t off = (size_t)m * S_K + d;
                float v = acc[mt][nt][reg];
                if (ACCUM) v += ob[off];
                ob[off] = v;
            }
}

extern "C" void kernel_launch(void* const* d_in, const int* in_sizes, int n_in,
                              void* d_out, int out_size, void* d_ws, size_t ws_size,
                              hipStream_t stream) {
    // inputs (fp32): 0=x (UNUSED), 1=attentionXFull, 2=attentionYFull,
    //                3=valueFull, 4=shift, 5=bias
    const float* attX = (const float*)d_in[1];
    const float* attY = (const float*)d_in[2];
    const float* V    = (const float*)d_in[3];
    const float* shp  = (const float*)d_in[4];
    const float* bip  = (const float*)d_in[5];
    float* out = (float*)d_out;

    const size_t A_ELEMS  = 4194304;    // per att tensor (u16)
    const size_t VT_ELEMS = 33554432;   // per V retile (u16)
    const size_t NEED = (2 * A_ELEMS + 2 * VT_ELEMS) * sizeof(unsigned short);  // 151MB

    if (ws_size >= NEED) {
        unsigned short* aXw = (unsigned short*)d_ws;
        unsigned short* aYw = aXw + A_ELEMS;
        unsigned short* vtX = aYw + A_ELEMS;
        unsigned short* vtY = vtX + VT_ELEMS;
        prep_sig<<<dim3(1024), dim3(256), 0, stream>>>(attX, attY, aXw, aYw, shp, bip);
        retile<<<dim3(1024), dim3(256), 0, stream>>>(V, vtX, 512LL, 2097152LL, 32768LL);
        retile<<<dim3(1024), dim3(256), 0, stream>>>(V, vtY, 32768LL, 2097152LL, 512LL);
        gauss_mfma<<<dim3(8192), dim3(64), 0, stream>>>(aXw, aYw, vtX, vtY, out);
    } else {
        dim3 blk(256);
        dim3 grid(16 * 64 * 4);
        gauss_gemm<32768, 512, false><<<grid, blk, 0, stream>>>(attX, V, out, shp, bip);
        gauss_gemm<512, 32768, true><<<grid, blk, 0, stream>>>(attY, V, out, shp, bip);
    }
}

// Round 3
// 465.645 us; speedup vs baseline: 1.0576x; 1.0576x over previous
//
#include <hip/hip_runtime.h>
#include <stdint.h>

// GaussianTrans R6: out[b,r,c,d] = sum_h sig(disX[c,h]+attX[b,r,c,h]) * V[b,r,h,d]
//                                + sum_w sig(disY[r,w]+attY[b,c,r,w]) * V[b,w,c,d]
// B=16, H=W=64, D=512. fp32 I/O; bf16 MFMA, fp32 accum, fp16 X-partial park.
// prep_sig: A' = bf16(sigmoid(dis+att)) once (ws, 16.8MB).
// gauss_fused2: NO V retile, NO V LDS staging. MFMA B-frag (col=l15=d, k=quad*8+j)
// is loaded directly from fp32 V as 16 coalesced-64B-segment scalar loads; A-frags
// (A'X m=c / A'Y m=r) are direct b128 loads. X->Y orientation mismatch bridged by
// 8.4KB/wave fp16 LDS park. 4 independent waves/block (zero barriers), 16 waves/CU,
// XCD-pinned (b,dt) so A'[b] (2MB) + V-slab (256KB) stay L2-resident.
// R5 lesson: retile passes cost 330us and main was HBM-latency-bound at 12 waves/CU.

typedef __attribute__((ext_vector_type(8))) __bf16 bf16x8;
typedef __attribute__((ext_vector_type(8))) short short8;
typedef __attribute__((ext_vector_type(4))) float f32x4;
typedef __attribute__((ext_vector_type(4))) unsigned int uint4v;
typedef __attribute__((ext_vector_type(4))) unsigned short u16x4;

union U8 { short8 s; bf16x8 b; unsigned short u[8]; uint4v q; };

__device__ __forceinline__ unsigned short f2bf(float f) {
    union { float f; unsigned int i; } v; v.f = f;
    return (unsigned short)((v.i + 0x7fffu + ((v.i >> 16) & 1u)) >> 16);  // RNE
}
__device__ __forceinline__ float fsigmoid(float x) {
    float e = __builtin_amdgcn_exp2f(-1.44269504f * x);   // exp(-x)
    return __builtin_amdgcn_rcpf(1.0f + e);
}
__device__ __forceinline__ unsigned short f2h(float f) {
    union { _Float16 h; unsigned short u; } v; v.h = (_Float16)f; return v.u;
}
__device__ __forceinline__ float h2f(unsigned short u) {
    union { _Float16 h; unsigned short us; } v; v.us = u; return (float)v.h;
}

// ---------------- prep: A' = bf16(sigmoid(dis + att)) ----------------
__device__ __forceinline__ void sig16(const float* __restrict__ in,
                                      unsigned short* __restrict__ outp,
                                      int l0, int sec, float shift, float bias) {
    f32x4 v[4];
#pragma unroll
    for (int j = 0; j < 4; ++j) v[j] = *(const f32x4*)(in + 4 * j);
    U8 r0, r1;
#pragma unroll
    for (int e = 0; e < 16; ++e) {
        float dd = (float)(l0 + e - sec);
        float dis = -(shift * dd * dd + bias);
        unsigned short us = f2bf(fsigmoid(dis + v[e >> 2][e & 3]));
        if (e < 8) r0.u[e] = us; else r1.u[e - 8] = us;
    }
    *(uint4v*)(outp) = r0.q;
    *(uint4v*)(outp + 8) = r1.q;
}

__global__ __launch_bounds__(256)
void prep_sig(const float* __restrict__ attX, const float* __restrict__ attY,
              unsigned short* __restrict__ aX, unsigned short* __restrict__ aY,
              const float* __restrict__ shiftp, const float* __restrict__ biasp) {
    const float shift = shiftp[0];
    const float bias  = biasp[0];
    const size_t base = ((size_t)blockIdx.x * 256 + threadIdx.x) * 16;
    const int sec = (int)((base >> 6) & 63);
    const int l0  = (int)(base & 63);
    sig16(attX + base, aX + base, l0, sec, shift, bias);
    sig16(attY + base, aY + base, l0, sec, shift, bias);
}

// ---------------- fused: direct-load MFMA, per-wave park ----------------
// Block = (b, dt [32 d-floats], rt [16 r]); 4 waves = ct quadrants; no barriers.
// Wave owns out[b, rt*16+0..15, ct*16+0..15, dt*32+0..31] (two d16 chunks).
// X (per rr): m=c: A=A'X[b,r, c=ct16+l15, h] b128; B=V[b,r, h=quad*8+j, d=l15+d0]
//   16 scalar loads (4x64B segments/inst, L1-shared across ct-waves).
//   acc(c=quad*4+g, d=l15) -> park[d:264][r:16][c] fp16 b64 write.
// Y (per cc): m=r: A=A'Y[b,c, r=rt16+l15, w] b128; B=V[b, w, c, d] 16 scalar loads.
//   acc(r=quad*4+g, d=l15) + park(d=l15, r=quad*4+g, c=cc) -> scalar f32 stores
//   (lanes l15 -> consecutive d: 4x64B segments per store inst).
__global__ __launch_bounds__(256, 4)
void gauss_fused2(const unsigned short* __restrict__ aX,
                  const unsigned short* __restrict__ aY,
                  const float* __restrict__ V,
                  float* __restrict__ out) {
    __shared__ unsigned short park[4 * 4224];  // 8448B per wave, 33792B total

    // XCD pin: p%8 -> XCD; seq covers (b_hi, dt, rt) dt-major so the 4 rt-blocks
    // of a (b,dt) group are co-resident and share the V slab + A'[b] in L2.
    const int p   = blockIdx.x;
    const int xcd = p & 7;
    const int s   = p >> 3;
    const int b   = xcd + ((s >> 6) << 3);
    const int rem = s & 63;
    const int dt  = rem >> 2;   // 0..15 (d32 slabs)
    const int rt  = rem & 3;

    const int t    = threadIdx.x;
    const int lane = t & 63;
    const int ct   = t >> 6;
    const int l15  = lane & 15, quad = lane >> 4;

    unsigned short* pk = &park[ct * 4224];

    const size_t vbase = (size_t)b * 2097152;
    const unsigned short* aXb = aX + (size_t)b * 262144;  // [r][c][h]
    const unsigned short* aYb = aY + (size_t)b * 262144;  // [c][r][w]

    for (int dc = 0; dc < 2; ++dc) {
        const int dcol = dt * 32 + dc * 16 + l15;

        // ---- X phase ----
        const float* vxw = V + vbase + (size_t)(rt * 16) * 32768 + dcol;     // +rr*32768 +h*512
        const unsigned short* axw = aXb + ((size_t)(rt * 16) * 64 + ct * 16 + l15) * 64 + quad * 8;
#pragma unroll 2
        for (int rr = 0; rr < 16; ++rr) {
            const float* vp = vxw + (size_t)rr * 32768;
            const unsigned short* ap = axw + (size_t)rr * 4096;
            f32x4 acc = (f32x4)0.0f;
#pragma unroll
            for (int ks = 0; ks < 2; ++ks) {
                const int h0 = ks * 32 + quad * 8;
                float vf[8];
#pragma unroll
                for (int j = 0; j < 8; ++j) vf[j] = vp[(h0 + j) * 512];
                U8 a; a.q = *(const uint4v*)(ap + ks * 32);
                U8 bb;
#pragma unroll
                for (int j = 0; j < 8; ++j) bb.u[j] = f2bf(vf[j]);
                acc = __builtin_amdgcn_mfma_f32_16x16x32_bf16(a.b, bb.b, acc, 0, 0, 0);
            }
            u16x4 w;
#pragma unroll
            for (int g = 0; g < 4; ++g) w[g] = f2h(acc[g]);
            *(u16x4*)&pk[l15 * 264 + rr * 16 + quad * 4] = w;
        }

        // ---- Y phase + epilogue (park dep is intra-wave: lgkmcnt only) ----
        const float* vyw = V + vbase + (size_t)(ct * 16) * 512 + dcol;       // +cc*512 +w*32768
        const unsigned short* ayw = aYb + ((size_t)(ct * 16) * 64 + rt * 16 + l15) * 64 + quad * 8;
        float* ow = out + vbase + (size_t)(rt * 16 + quad * 4) * 32768
                  + (size_t)(ct * 16) * 512 + dcol;                          // +g*32768 +cc*512
#pragma unroll 2
        for (int cc = 0; cc < 16; ++cc) {
            const float* vp = vyw + (size_t)cc * 512;
            const unsigned short* ap = ayw + (size_t)cc * 4096;
            f32x4 acc = (f32x4)0.0f;
#pragma unroll
            for (int ks = 0; ks < 2; ++ks) {
                const int w0 = ks * 32 + quad * 8;
                float vf[8];
#pragma unroll
                for (int j = 0; j < 8; ++j) vf[j] = vp[(size_t)(w0 + j) * 32768];
                U8 a; a.q = *(const uint4v*)(ap + ks * 32);
                U8 bb;
#pragma unroll
                for (int j = 0; j < 8; ++j) bb.u[j] = f2bf(vf[j]);
                acc = __builtin_amdgcn_mfma_f32_16x16x32_bf16(a.b, bb.b, acc, 0, 0, 0);
            }
#pragma unroll
            for (int g = 0; g < 4; ++g) {
                float xv = h2f(pk[l15 * 264 + (quad * 4 + g) * 16 + cc]);
                ow[(size_t)g * 32768 + (size_t)cc * 512] = acc[g] + xv;
            }
        }
    }
}

// ---------------- fallback (ws too small): proven two-pass kernel ----------------
template <int S_I, int S_K, bool ACCUM>
__global__ __launch_bounds__(256)
void gauss_gemm(const float* __restrict__ att,
                const float* __restrict__ V,
                float* __restrict__ out,
                const float* __restrict__ shiftp,
                const float* __restrict__ biasp) {
    __shared__ unsigned short S[4096];
    __shared__ unsigned short VT[128 * 66];

    const int bid    = blockIdx.x;
    const int dq     = bid & 3;
    const int i      = (bid >> 2) & 63;
    const int b      = bid >> 8;
    const int t      = threadIdx.x;
    const int dstart = dq * 128;

    const float shift = shiftp[0];
    const float bias  = biasp[0];
    const size_t base = (size_t)b * 2097152 + (size_t)i * S_I;

    const float* ab = att + (size_t)(b * 64 + i) * 4096;
#pragma unroll
    for (int chunk = 0; chunk < 2; ++chunk) {
        int flat = t + chunk * 256;
        int qd = flat >> 6, m = flat & 63;
        const float* ap = ab + m * 64 + qd * 8;
        f32x4 av0 = *(const f32x4*)(ap);
        f32x4 av1 = *(const f32x4*)(ap + 4);
        U8 res;
#pragma unroll
        for (int j = 0; j < 8; ++j) {
            float a    = (j < 4) ? av0[j & 3] : av1[j & 3];
            float diff = (float)(qd * 8 + j - m);
            float dis  = -(shift * diff * diff + bias);
            res.u[j]   = f2bf(fsigmoid(dis + a));
        }
        *(short8*)(&S[flat * 8]) = res.s;
    }
    {
        const float* vb = V + base + dstart;
        const int d4 = t & 31;
        const int h0 = t >> 5;
#pragma unroll
        for (int it = 0; it < 8; ++it) {
            const int h = h0 + it * 8;
            f32x4 v = *(const f32x4*)(vb + (size_t)h * S_K + 4 * d4);
#pragma unroll
            for (int u = 0; u < 4; ++u)
                VT[(4 * d4 + u) * 66 + h] = f2bf(v[u]);
        }
    }
    __syncthreads();

    const int lane = t & 63, wid = t >> 6;
    const int l15 = lane & 15, quad = lane >> 4;

    f32x4 acc[4][2];
#pragma unroll
    for (int mt = 0; mt < 4; ++mt)
#pragma unroll
        for (int nt = 0; nt < 2; ++nt) acc[mt][nt] = (f32x4)0.0f;

#pragma unroll
    for (int ks = 0; ks < 2; ++ks) {
        bf16x8 af[4];
#pragma unroll
        for (int mt = 0; mt < 4; ++mt) {
            U8 a;
            a.s = *(const short8*)(&S[((ks * 4 + quad) * 64 + mt * 16 + l15) * 8]);
            af[mt] = a.b;
        }
        const int h = ks * 32 + quad * 8;
#pragma unroll
        for (int nt = 0; nt < 2; ++nt) {
            const int dloc = wid * 32 + nt * 16 + l15;
            const unsigned short* vp = &VT[dloc * 66 + h];
            U8 bvec;
            uint4v qv;
#pragma unroll
            for (int u = 0; u < 4; ++u) qv[u] = *(const unsigned int*)(vp + 2 * u);
            bvec.q = qv;
#pragma unroll
            for (int mt = 0; mt < 4; ++mt)
                acc[mt][nt] = __builtin_amdgcn_mfma_f32_16x16x32_bf16(
                    af[mt], bvec.b, acc[mt][nt], 0, 0, 0);
        }
    }

    float* ob = out + base + dstart;
#pragma unroll
    for (int mt = 0; mt < 4; ++mt)
#pragma unroll
        for (int nt = 0; nt < 2; ++nt)
#pragma unroll
            for (int reg = 0; reg < 4; ++reg) {
                int m = mt * 16 + quad * 4 + reg;
                int d = wid * 32 + nt * 16 + l15;
                size_t off = (size_t)m * S_K + d;
                float v = acc[mt][nt][reg];
                if (ACCUM) v += ob[off];
                ob[off] = v;
            }
}

extern "C" void kernel_launch(void* const* d_in, const int* in_sizes, int n_in,
                              void* d_out, int out_size, void* d_ws, size_t ws_size,
                              hipStream_t stream) {
    // inputs (fp32): 0=x (UNUSED), 1=attentionXFull, 2=attentionYFull,
    //                3=valueFull, 4=shift, 5=bias
    const float* attX = (const float*)d_in[1];
    const float* attY = (const float*)d_in[2];
    const float* V    = (const float*)d_in[3];
    const float* shp  = (const float*)d_in[4];
    const float* bip  = (const float*)d_in[5];
    float* out = (float*)d_out;

    const size_t A_ELEMS = 4194304;  // per att tensor (u16)
    const size_t NEED = 2 * A_ELEMS * sizeof(unsigned short);  // 16.8MB

    if (ws_size >= NEED) {
        unsigned short* aXw = (unsigned short*)d_ws;
        unsigned short* aYw = aXw + A_ELEMS;
        prep_sig<<<dim3(1024), dim3(256), 0, stream>>>(attX, attY, aXw, aYw, shp, bip);
        gauss_fused2<<<dim3(1024), dim3(256), 0, stream>>>(aXw, aYw, V, out);
    } else {
        dim3 blk(256);
        dim3 grid(16 * 64 * 4);
        gauss_gemm<32768, 512, false><<<grid, blk, 0, stream>>>(attX, V, out, shp, bip);
        gauss_gemm<512, 32768, true><<<grid, blk, 0, stream>>>(attY, V, out, shp, bip);
    }
}

// Round 4
// 379.052 us; speedup vs baseline: 1.2992x; 1.2284x over previous
//
#include <hip/hip_runtime.h>
#include <stdint.h>

// GaussianTrans R7: out[b,r,c,d] = sum_h sig(disX[c,h]+attX[b,r,c,h]) * V[b,r,h,d]
//                                + sum_w sig(disY[r,w]+attY[b,c,r,w]) * V[b,w,c,d]
// B=16, H=W=64, D=512. fp32 I/O; bf16 MFMA, fp32 accum, fp16 X-partial park.
// prep_sig: A' = bf16(sigmoid(dis+att)) once (ws, 16.8MB).
// gauss_fused3: wave tile r16 x c16 x d32. V loaded as f32x2 at d=2*l15: 16 lanes
// cover a full 128B line per instruction (R6 read 64B halves an entire phase apart
// -> 2x V refetch, FETCH 376MB). Each f32x2 feeds TWO interleaved MFMA tiles
// (col l15 <-> d=2*l15+e), so V-load instruction count drops 4x. Park = full wave
// tile fp16 (18.1KB/wave, bank-tuned strides), 74KB/block -> 2 blocks/CU; rr-loop
// ILP (16 independent load batches) covers L2 latency. One b per XCD (64 blocks =
// XCD concurrency) so rt-twins' Y phases co-run and each (b,dt) slab is HBM-read ~1x.
// Stores: f32x2 per lane at d=2*l15 -> full-line coalesced writes.

typedef __attribute__((ext_vector_type(8))) __bf16 bf16x8;
typedef __attribute__((ext_vector_type(8))) short short8;
typedef __attribute__((ext_vector_type(2))) float f32x2;
typedef __attribute__((ext_vector_type(4))) float f32x4;
typedef __attribute__((ext_vector_type(4))) unsigned int uint4v;
typedef __attribute__((ext_vector_type(4))) unsigned short u16x4;

union U8 { short8 s; bf16x8 b; unsigned short u[8]; uint4v q; };

__device__ __forceinline__ unsigned short f2bf(float f) {
    union { float f; unsigned int i; } v; v.f = f;
    return (unsigned short)((v.i + 0x7fffu + ((v.i >> 16) & 1u)) >> 16);  // RNE
}
__device__ __forceinline__ float fsigmoid(float x) {
    float e = __builtin_amdgcn_exp2f(-1.44269504f * x);   // exp(-x)
    return __builtin_amdgcn_rcpf(1.0f + e);
}
__device__ __forceinline__ unsigned short f2h(float f) {
    union { _Float16 h; unsigned short u; } v; v.h = (_Float16)f; return v.u;
}
__device__ __forceinline__ float h2f(unsigned short u) {
    union { _Float16 h; unsigned short us; } v; v.us = u; return (float)v.h;
}

// park u16 layout [d2(16)][r(16)][c(16)][e(2)]; strides (u16): d2=580, r=36, c=2.
// 580 u16 = 1160B = 290 dw: bank rotates 2 per d2 (l15) -> write ~2-way, read <=4-way.
// Per-wave size = 16*580 = 9280 u16 = 18560B; 4 waves = 74240B -> 2 blocks/CU.
__device__ __forceinline__ int park_off(int d2, int r, int c, int e) {
    return d2 * 580 + r * 36 + c * 2 + e;
}

// ---------------- prep: A' = bf16(sigmoid(dis + att)) ----------------
__device__ __forceinline__ void sig16(const float* __restrict__ in,
                                      unsigned short* __restrict__ outp,
                                      int l0, int sec, float shift, float bias) {
    f32x4 v[4];
#pragma unroll
    for (int j = 0; j < 4; ++j) v[j] = *(const f32x4*)(in + 4 * j);
    U8 r0, r1;
#pragma unroll
    for (int e = 0; e < 16; ++e) {
        float dd = (float)(l0 + e - sec);
        float dis = -(shift * dd * dd + bias);
        unsigned short us = f2bf(fsigmoid(dis + v[e >> 2][e & 3]));
        if (e < 8) r0.u[e] = us; else r1.u[e - 8] = us;
    }
    *(uint4v*)(outp) = r0.q;
    *(uint4v*)(outp + 8) = r1.q;
}

__global__ __launch_bounds__(256)
void prep_sig(const float* __restrict__ attX, const float* __restrict__ attY,
              unsigned short* __restrict__ aX, unsigned short* __restrict__ aY,
              const float* __restrict__ shiftp, const float* __restrict__ biasp) {
    const float shift = shiftp[0];
    const float bias  = biasp[0];
    const size_t base = ((size_t)blockIdx.x * 256 + threadIdx.x) * 16;
    const int sec = (int)((base >> 6) & 63);
    const int l0  = (int)(base & 63);
    sig16(attX + base, aX + base, l0, sec, shift, bias);
    sig16(attY + base, aY + base, l0, sec, shift, bias);
}

// ---------------- fused: f32x2 direct-load MFMA, d32 wave tile ----------------
// Block = (b, dt [32 d], rt [16 r]); 4 waves = ct quadrants; zero barriers.
// X (per rr): A = A'X[b,r, c=ct16+l15, h] b128 (row=c); B = V[b,r, h=k, 2l15+e]
//   f32x2 x8 per ks; two accs (e=0,1); park u16x8 -> [l15][rr][quad*4..+3][e].
// Y (per cc): A = A'Y[b,c, r=rt16+l15, w] b128 (row=r); B = V[b, w, c, 2l15+e];
//   epilogue: acc_e[g] + park(l15, quad*4+g, cc, e) -> f32x2 store (full lines).
__global__ __launch_bounds__(256, 2)
void gauss_fused3(const unsigned short* __restrict__ aX,
                  const unsigned short* __restrict__ aY,
                  const float* __restrict__ V,
                  float* __restrict__ out) {
    __shared__ unsigned short park[4 * 9280];  // 74240B -> 2 blocks/CU

    // XCD pin: p%8 -> XCD; s = rt + 4*dt + 64*b_hi. One b per XCD at a time
    // (64 blocks = 2/CU x 32 CU); rt-twins adjacent so Y slab reads coincide.
    const int p   = blockIdx.x;
    const int xcd = p & 7;
    const int s   = p >> 3;
    const int b   = xcd + ((s >> 6) << 3);
    const int dt  = (s >> 2) & 15;
    const int rt  = s & 3;

    const int t    = threadIdx.x;
    const int lane = t & 63;
    const int ct   = t >> 6;
    const int l15  = lane & 15, quad = lane >> 4;
    const int d0   = dt * 32;

    unsigned short* mypark = &park[ct * 9280];

    const size_t vbase = (size_t)b * 2097152;
    const unsigned short* aXb = aX + (size_t)b * 262144;  // [r][c][h]
    const unsigned short* aYb = aY + (size_t)b * 262144;  // [c][r][w]

    // ---- X phase ----
    {
        const float* vxw = V + vbase + (size_t)(rt * 16) * 32768 + d0 + 2 * l15;
        const unsigned short* axw = aXb + ((size_t)(rt * 16) * 64 + ct * 16 + l15) * 64 + quad * 8;
#pragma unroll 2
        for (int rr = 0; rr < 16; ++rr) {
            const float* vp = vxw + (size_t)rr * 32768;
            const unsigned short* ap = axw + (size_t)rr * 4096;
            f32x4 acc0 = (f32x4)0.0f, acc1 = (f32x4)0.0f;
#pragma unroll
            for (int ks = 0; ks < 2; ++ks) {
                const int h0 = ks * 32 + quad * 8;
                f32x2 vf[8];
#pragma unroll
                for (int j = 0; j < 8; ++j) vf[j] = *(const f32x2*)(vp + (h0 + j) * 512);
                U8 a; a.q = *(const uint4v*)(ap + ks * 32);
                U8 b0, b1;
#pragma unroll
                for (int j = 0; j < 8; ++j) { b0.u[j] = f2bf(vf[j][0]); b1.u[j] = f2bf(vf[j][1]); }
                acc0 = __builtin_amdgcn_mfma_f32_16x16x32_bf16(a.b, b0.b, acc0, 0, 0, 0);
                acc1 = __builtin_amdgcn_mfma_f32_16x16x32_bf16(a.b, b1.b, acc1, 0, 0, 0);
            }
            U8 pk;
#pragma unroll
            for (int g = 0; g < 4; ++g) { pk.u[g * 2] = f2h(acc0[g]); pk.u[g * 2 + 1] = f2h(acc1[g]); }
            *(uint4v*)&mypark[park_off(l15, rr, quad * 4, 0)] = pk.q;
        }
    }

    // ---- Y phase + epilogue (park dep intra-wave: lgkmcnt only, no barrier) ----
    {
        const float* vyw = V + vbase + (size_t)(ct * 16) * 512 + d0 + 2 * l15;
        const unsigned short* ayw = aYb + ((size_t)(ct * 16) * 64 + rt * 16 + l15) * 64 + quad * 8;
        float* ow = out + vbase + (size_t)(rt * 16 + quad * 4) * 32768
                  + (size_t)(ct * 16) * 512 + d0 + 2 * l15;
#pragma unroll 2
        for (int cc = 0; cc < 16; ++cc) {
            const float* vp = vyw + (size_t)cc * 512;
            const unsigned short* ap = ayw + (size_t)cc * 4096;
            f32x4 acc0 = (f32x4)0.0f, acc1 = (f32x4)0.0f;
#pragma unroll
            for (int ks = 0; ks < 2; ++ks) {
                const int w0 = ks * 32 + quad * 8;
                f32x2 vf[8];
#pragma unroll
                for (int j = 0; j < 8; ++j) vf[j] = *(const f32x2*)(vp + (size_t)(w0 + j) * 32768);
                U8 a; a.q = *(const uint4v*)(ap + ks * 32);
                U8 b0, b1;
#pragma unroll
                for (int j = 0; j < 8; ++j) { b0.u[j] = f2bf(vf[j][0]); b1.u[j] = f2bf(vf[j][1]); }
                acc0 = __builtin_amdgcn_mfma_f32_16x16x32_bf16(a.b, b0.b, acc0, 0, 0, 0);
                acc1 = __builtin_amdgcn_mfma_f32_16x16x32_bf16(a.b, b1.b, acc1, 0, 0, 0);
            }
#pragma unroll
            for (int g = 0; g < 4; ++g) {
                const unsigned short* pp = &mypark[park_off(l15, quad * 4 + g, cc, 0)];
                f32x2 res;
                res[0] = acc0[g] + h2f(pp[0]);
                res[1] = acc1[g] + h2f(pp[1]);
                *(f32x2*)(ow + (size_t)g * 32768 + (size_t)cc * 512) = res;
            }
        }
    }
}

// ---------------- fallback (ws too small): proven two-pass kernel ----------------
template <int S_I, int S_K, bool ACCUM>
__global__ __launch_bounds__(256)
void gauss_gemm(const float* __restrict__ att,
                const float* __restrict__ V,
                float* __restrict__ out,
                const float* __restrict__ shiftp,
                const float* __restrict__ biasp) {
    __shared__ unsigned short S[4096];
    __shared__ unsigned short VT[128 * 66];

    const int bid    = blockIdx.x;
    const int dq     = bid & 3;
    const int i      = (bid >> 2) & 63;
    const int b      = bid >> 8;
    const int t      = threadIdx.x;
    const int dstart = dq * 128;

    const float shift = shiftp[0];
    const float bias  = biasp[0];
    const size_t base = (size_t)b * 2097152 + (size_t)i * S_I;

    const float* ab = att + (size_t)(b * 64 + i) * 4096;
#pragma unroll
    for (int chunk = 0; chunk < 2; ++chunk) {
        int flat = t + chunk * 256;
        int qd = flat >> 6, m = flat & 63;
        const float* ap = ab + m * 64 + qd * 8;
        f32x4 av0 = *(const f32x4*)(ap);
        f32x4 av1 = *(const f32x4*)(ap + 4);
        U8 res;
#pragma unroll
        for (int j = 0; j < 8; ++j) {
            float a    = (j < 4) ? av0[j & 3] : av1[j & 3];
            float diff = (float)(qd * 8 + j - m);
            float dis  = -(shift * diff * diff + bias);
            res.u[j]   = f2bf(fsigmoid(dis + a));
        }
        *(short8*)(&S[flat * 8]) = res.s;
    }
    {
        const float* vb = V + base + dstart;
        const int d4 = t & 31;
        const int h0 = t >> 5;
#pragma unroll
        for (int it = 0; it < 8; ++it) {
            const int h = h0 + it * 8;
            f32x4 v = *(const f32x4*)(vb + (size_t)h * S_K + 4 * d4);
#pragma unroll
            for (int u = 0; u < 4; ++u)
                VT[(4 * d4 + u) * 66 + h] = f2bf(v[u]);
        }
    }
    __syncthreads();

    const int lane = t & 63, wid = t >> 6;
    const int l15 = lane & 15, quad = lane >> 4;

    f32x4 acc[4][2];
#pragma unroll
    for (int mt = 0; mt < 4; ++mt)
#pragma unroll
        for (int nt = 0; nt < 2; ++nt) acc[mt][nt] = (f32x4)0.0f;

#pragma unroll
    for (int ks = 0; ks < 2; ++ks) {
        bf16x8 af[4];
#pragma unroll
        for (int mt = 0; mt < 4; ++mt) {
            U8 a;
            a.s = *(const short8*)(&S[((ks * 4 + quad) * 64 + mt * 16 + l15) * 8]);
            af[mt] = a.b;
        }
        const int h = ks * 32 + quad * 8;
#pragma unroll
        for (int nt = 0; nt < 2; ++nt) {
            const int dloc = wid * 32 + nt * 16 + l15;
            const unsigned short* vp = &VT[dloc * 66 + h];
            U8 bvec;
            uint4v qv;
#pragma unroll
            for (int u = 0; u < 4; ++u) qv[u] = *(const unsigned int*)(vp + 2 * u);
            bvec.q = qv;
#pragma unroll
            for (int mt = 0; mt < 4; ++mt)
                acc[mt][nt] = __builtin_amdgcn_mfma_f32_16x16x32_bf16(
                    af[mt], bvec.b, acc[mt][nt], 0, 0, 0);
        }
    }

    float* ob = out + base + dstart;
#pragma unroll
    for (int mt = 0; mt < 4; ++mt)
#pragma unroll
        for (int nt = 0; nt < 2; ++nt)
#pragma unroll
            for (int reg = 0; reg < 4; ++reg) {
                int m = mt * 16 + quad * 4 + reg;
                int d = wid * 32 + nt * 16 + l15;
                size_t off = (size_t)m * S_K + d;
                float v = acc[mt][nt][reg];
                if (ACCUM) v += ob[off];
                ob[off] = v;
            }
}

extern "C" void kernel_launch(void* const* d_in, const int* in_sizes, int n_in,
                              void* d_out, int out_size, void* d_ws, size_t ws_size,
                              hipStream_t stream) {
    // inputs (fp32): 0=x (UNUSED), 1=attentionXFull, 2=attentionYFull,
    //                3=valueFull, 4=shift, 5=bias
    const float* attX = (const float*)d_in[1];
    const float* attY = (const float*)d_in[2];
    const float* V    = (const float*)d_in[3];
    const float* shp  = (const float*)d_in[4];
    const float* bip  = (const float*)d_in[5];
    float* out = (float*)d_out;

    const size_t A_ELEMS = 4194304;  // per att tensor (u16)
    const size_t NEED = 2 * A_ELEMS * sizeof(unsigned short);  // 16.8MB

    if (ws_size >= NEED) {
        unsigned short* aXw = (unsigned short*)d_ws;
        unsigned short* aYw = aXw + A_ELEMS;
        prep_sig<<<dim3(1024), dim3(256), 0, stream>>>(attX, attY, aXw, aYw, shp, bip);
        gauss_fused3<<<dim3(1024), dim3(256), 0, stream>>>(aXw, aYw, V, out);
    } else {
        dim3 blk(256);
        dim3 grid(16 * 64 * 4);
        gauss_gemm<32768, 512, false><<<grid, blk, 0, stream>>>(attX, V, out, shp, bip);
        gauss_gemm<512, 32768, true><<<grid, blk, 0, stream>>>(attY, V, out, shp, bip);
    }
}